// Round 3
// baseline (359.530 us; speedup 1.0000x reference)
//
#include <hip/hip_runtime.h>
#include <math.h>

#define IN_CH 32
#define K_OUT 4

// ---------------------------------------------------------------------------
// Kernel 1: z[n][k][i] = sum_j T[k][i][j] * x[n][j]
// ---------------------------------------------------------------------------
__global__ void precompute_z_kernel(const float* __restrict__ x,
                                    const float* __restrict__ T,
                                    float* __restrict__ z,
                                    int n_nodes) {
    __shared__ float Ts[K_OUT * IN_CH * IN_CH];
    for (int t = threadIdx.x; t < K_OUT * IN_CH * IN_CH; t += blockDim.x)
        Ts[t] = T[t];
    __syncthreads();

    const int ki = threadIdx.x;          // 0..127  ->  k = ki>>5, i = ki&31
    const float* Trow = Ts + ki * IN_CH;

    for (int n = blockIdx.x; n < n_nodes; n += gridDim.x) {
        const float* xr = x + (size_t)n * IN_CH;
        float sum = 0.f;
#pragma unroll
        for (int j = 0; j < IN_CH; ++j)
            sum = fmaf(Trow[j], xr[j], sum);
        z[(size_t)n * (K_OUT * IN_CH) + ki] = sum;
    }
}

// ---------------------------------------------------------------------------
// Counting-sort pipeline: edges bucketed by dst node so the edge kernel sees
// monotone dst -> z-row gathers become L1 broadcast hits.
// ---------------------------------------------------------------------------
__global__ void zero_kernel(int* __restrict__ p, int n) {
    int i = blockIdx.x * blockDim.x + threadIdx.x;
    if (i < n) p[i] = 0;
}

__global__ void hist_kernel(const int* __restrict__ dst,
                            int* __restrict__ hist, int n_edges) {
    int e = blockIdx.x * blockDim.x + threadIdx.x;
    if (e < n_edges) atomicAdd(&hist[dst[e]], 1);   // ~32 edges/bucket: low contention
}

// Single-block exclusive scan over n buckets (n ~ 50K): each of 1024 threads
// serial-scans a contiguous chunk, block-scans the chunk sums, then writes.
__global__ __launch_bounds__(1024)
void scan_kernel(const int* __restrict__ hist, int* __restrict__ cursor, int n) {
    __shared__ int s[1024];
    const int tid = threadIdx.x;
    const int C = (n + 1023) >> 10;
    const int lo = min(tid * C, n);
    const int hi = min(lo + C, n);
    int sum = 0;
    for (int i = lo; i < hi; ++i) sum += hist[i];
    s[tid] = sum;
    __syncthreads();
    for (int off = 1; off < 1024; off <<= 1) {
        int t = (tid >= off) ? s[tid - off] : 0;
        __syncthreads();
        s[tid] += t;
        __syncthreads();
    }
    int run = s[tid] - sum;           // exclusive offset of this chunk
    for (int i = lo; i < hi; ++i) { cursor[i] = run; run += hist[i]; }
}

__global__ void scatter_kernel(const int* __restrict__ src,
                               const int* __restrict__ dst,
                               int* __restrict__ cursor,
                               int4* __restrict__ rec, int n_edges) {
    int e = blockIdx.x * blockDim.x + threadIdx.x;
    if (e >= n_edges) return;
    int d = dst[e];
    int pos = atomicAdd(&cursor[d], 1);
    rec[pos] = make_int4(src[e], d, e, 0);
}

// ---------------------------------------------------------------------------
// Main edge kernel, quad-per-edge, consuming dst-sorted records.
// Lane l owns x-chunk l (32 B) and the matching slice of all 4 z_k rows.
// Quad transpose-reduce leaves lane l holding maps[e][l]; store to out[orig].
// ---------------------------------------------------------------------------
__global__ __launch_bounds__(256)
void edge_kernel_sorted(const float* __restrict__ x,
                        const float* __restrict__ z,
                        const int4* __restrict__ rec,
                        float* __restrict__ out,
                        int n_edges) {
    const int t = blockIdx.x * blockDim.x + threadIdx.x;
    const int ep = t >> 2;
    const int l = t & 3;
    if (ep >= n_edges) return;

    const int4 r = rec[ep];           // same 16B for all 4 lanes: L1 broadcast
    const int s = r.x;
    const int d = r.y;

    const float4* xs = (const float4*)(x + (size_t)s * IN_CH) + l * 2;
    const float4* zd = (const float4*)(z + (size_t)d * (K_OUT * IN_CH)) + l * 2;

    float4 xa = xs[0];
    float4 xb = xs[1];
    float4 z0a = zd[0],  z0b = zd[1];
    float4 z1a = zd[8],  z1b = zd[9];
    float4 z2a = zd[16], z2b = zd[17];
    float4 z3a = zd[24], z3b = zd[25];

    float p0 = 0.f, p1 = 0.f, p2 = 0.f, p3 = 0.f;
    p0 = fmaf(xa.x, z0a.x, p0); p0 = fmaf(xa.y, z0a.y, p0);
    p0 = fmaf(xa.z, z0a.z, p0); p0 = fmaf(xa.w, z0a.w, p0);
    p0 = fmaf(xb.x, z0b.x, p0); p0 = fmaf(xb.y, z0b.y, p0);
    p0 = fmaf(xb.z, z0b.z, p0); p0 = fmaf(xb.w, z0b.w, p0);

    p1 = fmaf(xa.x, z1a.x, p1); p1 = fmaf(xa.y, z1a.y, p1);
    p1 = fmaf(xa.z, z1a.z, p1); p1 = fmaf(xa.w, z1a.w, p1);
    p1 = fmaf(xb.x, z1b.x, p1); p1 = fmaf(xb.y, z1b.y, p1);
    p1 = fmaf(xb.z, z1b.z, p1); p1 = fmaf(xb.w, z1b.w, p1);

    p2 = fmaf(xa.x, z2a.x, p2); p2 = fmaf(xa.y, z2a.y, p2);
    p2 = fmaf(xa.z, z2a.z, p2); p2 = fmaf(xa.w, z2a.w, p2);
    p2 = fmaf(xb.x, z2b.x, p2); p2 = fmaf(xb.y, z2b.y, p2);
    p2 = fmaf(xb.z, z2b.z, p2); p2 = fmaf(xb.w, z2b.w, p2);

    p3 = fmaf(xa.x, z3a.x, p3); p3 = fmaf(xa.y, z3a.y, p3);
    p3 = fmaf(xa.z, z3a.z, p3); p3 = fmaf(xa.w, z3a.w, p3);
    p3 = fmaf(xb.x, z3b.x, p3); p3 = fmaf(xb.y, z3b.y, p3);
    p3 = fmaf(xb.z, z3b.z, p3); p3 = fmaf(xb.w, z3b.w, p3);

    float send01 = (l & 1) ? p0 : p1;
    float recv01 = __shfl_xor(send01, 1);
    float a01 = ((l & 1) ? p1 : p0) + recv01;
    float send23 = (l & 1) ? p2 : p3;
    float recv23 = __shfl_xor(send23, 1);
    float a23 = ((l & 1) ? p3 : p2) + recv23;
    float send = (l & 2) ? a01 : a23;
    float recv = __shfl_xor(send, 2);
    float res = ((l & 2) ? a23 : a01) + recv;   // lane l = maps[e][l]

    out[((size_t)r.z << 2) + l] = tanhf(res);   // quad -> contiguous 16B store
}

// ---------------------------------------------------------------------------
// Tier-2 (ws fits z only): round-2 unsorted quad kernel.
// ---------------------------------------------------------------------------
__global__ __launch_bounds__(256)
void edge_kernel_quad(const float* __restrict__ x,
                      const float* __restrict__ z,
                      const int* __restrict__ src,
                      const int* __restrict__ dst,
                      float* __restrict__ out,
                      int n_edges) {
    const int t = blockIdx.x * blockDim.x + threadIdx.x;
    const int e = t >> 2;
    const int l = t & 3;
    if (e >= n_edges) return;

    const int s = src[e];
    const int d = dst[e];

    const float4* xs = (const float4*)(x + (size_t)s * IN_CH) + l * 2;
    const float4* zd = (const float4*)(z + (size_t)d * (K_OUT * IN_CH)) + l * 2;

    float4 xa = xs[0];
    float4 xb = xs[1];
    float4 z0a = zd[0],  z0b = zd[1];
    float4 z1a = zd[8],  z1b = zd[9];
    float4 z2a = zd[16], z2b = zd[17];
    float4 z3a = zd[24], z3b = zd[25];

    float p0 = 0.f, p1 = 0.f, p2 = 0.f, p3 = 0.f;
    p0 = fmaf(xa.x, z0a.x, p0); p0 = fmaf(xa.y, z0a.y, p0);
    p0 = fmaf(xa.z, z0a.z, p0); p0 = fmaf(xa.w, z0a.w, p0);
    p0 = fmaf(xb.x, z0b.x, p0); p0 = fmaf(xb.y, z0b.y, p0);
    p0 = fmaf(xb.z, z0b.z, p0); p0 = fmaf(xb.w, z0b.w, p0);

    p1 = fmaf(xa.x, z1a.x, p1); p1 = fmaf(xa.y, z1a.y, p1);
    p1 = fmaf(xa.z, z1a.z, p1); p1 = fmaf(xa.w, z1a.w, p1);
    p1 = fmaf(xb.x, z1b.x, p1); p1 = fmaf(xb.y, z1b.y, p1);
    p1 = fmaf(xb.z, z1b.z, p1); p1 = fmaf(xb.w, z1b.w, p1);

    p2 = fmaf(xa.x, z2a.x, p2); p2 = fmaf(xa.y, z2a.y, p2);
    p2 = fmaf(xa.z, z2a.z, p2); p2 = fmaf(xa.w, z2a.w, p2);
    p2 = fmaf(xb.x, z2b.x, p2); p2 = fmaf(xb.y, z2b.y, p2);
    p2 = fmaf(xb.z, z2b.z, p2); p2 = fmaf(xb.w, z2b.w, p2);

    p3 = fmaf(xa.x, z3a.x, p3); p3 = fmaf(xa.y, z3a.y, p3);
    p3 = fmaf(xa.z, z3a.z, p3); p3 = fmaf(xa.w, z3a.w, p3);
    p3 = fmaf(xb.x, z3b.x, p3); p3 = fmaf(xb.y, z3b.y, p3);
    p3 = fmaf(xb.z, z3b.z, p3); p3 = fmaf(xb.w, z3b.w, p3);

    float send01 = (l & 1) ? p0 : p1;
    float recv01 = __shfl_xor(send01, 1);
    float a01 = ((l & 1) ? p1 : p0) + recv01;
    float send23 = (l & 1) ? p2 : p3;
    float recv23 = __shfl_xor(send23, 1);
    float a23 = ((l & 1) ? p3 : p2) + recv23;
    float send = (l & 2) ? a01 : a23;
    float recv = __shfl_xor(send, 2);
    float r = ((l & 2) ? a23 : a01) + recv;

    out[t] = tanhf(r);
}

// ---------------------------------------------------------------------------
// Tier-3 fallback: direct quadratic form per edge (no workspace).
// ---------------------------------------------------------------------------
__global__ void edge_direct_kernel(const float* __restrict__ x,
                                   const float* __restrict__ T,
                                   const int* __restrict__ src,
                                   const int* __restrict__ dst,
                                   float* __restrict__ out,
                                   int n_edges) {
    int e = blockIdx.x * blockDim.x + threadIdx.x;
    if (e >= n_edges) return;

    const int s = src[e];
    const int d = dst[e];

    float xs[IN_CH], xd[IN_CH];
#pragma unroll
    for (int j = 0; j < IN_CH; ++j) {
        xs[j] = x[(size_t)s * IN_CH + j];
        xd[j] = x[(size_t)d * IN_CH + j];
    }

    float res[K_OUT];
#pragma unroll
    for (int k = 0; k < K_OUT; ++k) {
        float acc = 0.f;
        for (int i = 0; i < IN_CH; ++i) {
            const float* Trow = T + ((size_t)k * IN_CH + i) * IN_CH;
            float yi = 0.f;
#pragma unroll
            for (int j = 0; j < IN_CH; ++j)
                yi = fmaf(Trow[j], xd[j], yi);
            acc = fmaf(xs[i], yi, acc);
        }
        res[k] = tanhf(acc);
    }
    ((float4*)out)[e] = make_float4(res[0], res[1], res[2], res[3]);
}

extern "C" void kernel_launch(void* const* d_in, const int* in_sizes, int n_in,
                              void* d_out, int out_size, void* d_ws, size_t ws_size,
                              hipStream_t stream) {
    const float* x  = (const float*)d_in[0];
    const int*   ei = (const int*)d_in[1];
    const float* T  = (const float*)d_in[2];
    float* out      = (float*)d_out;

    const int n_nodes = in_sizes[0] / IN_CH;
    const int n_edges = in_sizes[1] / 2;
    const int* src = ei;
    const int* dst = ei + n_edges;

    // Workspace layout
    const size_t z_bytes    = (size_t)n_nodes * K_OUT * IN_CH * sizeof(float);
    const size_t hist_off   = (z_bytes + 255) & ~(size_t)255;
    const size_t hist_bytes = ((size_t)n_nodes * sizeof(int) + 255) & ~(size_t)255;
    const size_t cur_off    = hist_off + hist_bytes;
    const size_t rec_off    = (cur_off + hist_bytes + 255) & ~(size_t)255;
    const size_t need_full  = rec_off + (size_t)n_edges * sizeof(int4);

    const int threads = 256;
    const int eblocks = (n_edges + threads - 1) / threads;

    if (ws_size >= need_full) {
        float* z    = (float*)d_ws;
        int*   hist = (int*)((char*)d_ws + hist_off);
        int*   cur  = (int*)((char*)d_ws + cur_off);
        int4*  rec  = (int4*)((char*)d_ws + rec_off);

        precompute_z_kernel<<<4096, 128, 0, stream>>>(x, T, z, n_nodes);

        zero_kernel<<<(n_nodes + 255) / 256, 256, 0, stream>>>(hist, n_nodes);
        hist_kernel<<<eblocks, threads, 0, stream>>>(dst, hist, n_edges);
        scan_kernel<<<1, 1024, 0, stream>>>(hist, cur, n_nodes);
        scatter_kernel<<<eblocks, threads, 0, stream>>>(src, dst, cur, rec, n_edges);

        const long long total = (long long)n_edges * 4;
        const int blocks = (int)((total + threads - 1) / threads);
        edge_kernel_sorted<<<blocks, threads, 0, stream>>>(x, z, rec, out, n_edges);
    } else if (ws_size >= z_bytes) {
        float* z = (float*)d_ws;
        precompute_z_kernel<<<4096, 128, 0, stream>>>(x, T, z, n_nodes);
        const long long total = (long long)n_edges * 4;
        const int blocks = (int)((total + threads - 1) / threads);
        edge_kernel_quad<<<blocks, threads, 0, stream>>>(x, z, src, dst, out, n_edges);
    } else {
        edge_direct_kernel<<<eblocks, threads, 0, stream>>>(x, T, src, dst, out, n_edges);
    }
}

// Round 4
// 145.461 us; speedup vs baseline: 2.4717x; 2.4717x over previous
//
#include <hip/hip_runtime.h>
#include <math.h>

#define IN_CH 32
#define K_OUT 4
#define NB 8              // dst buckets == # XCDs; z-chunk = 50000/8*512B = 3.2MB < 4MB L2
#define SORT_TILE 4096
#define SORT_THREADS 256
#define EPT (SORT_TILE / SORT_THREADS)   // 16 edges per thread

// ---------------------------------------------------------------------------
// z[n][k][i] = sum_j T[k][i][j] * x[n][j]
// ---------------------------------------------------------------------------
__global__ void precompute_z_kernel(const float* __restrict__ x,
                                    const float* __restrict__ T,
                                    float* __restrict__ z,
                                    int n_nodes) {
    __shared__ float Ts[K_OUT * IN_CH * IN_CH];
    for (int t = threadIdx.x; t < K_OUT * IN_CH * IN_CH; t += blockDim.x)
        Ts[t] = T[t];
    __syncthreads();

    const int ki = threadIdx.x;          // 0..127 -> k = ki>>5, i = ki&31
    const float* Trow = Ts + ki * IN_CH;

    for (int n = blockIdx.x; n < n_nodes; n += gridDim.x) {
        const float* xr = x + (size_t)n * IN_CH;
        float sum = 0.f;
#pragma unroll
        for (int j = 0; j < IN_CH; ++j)
            sum = fmaf(Trow[j], xr[j], sum);
        z[(size_t)n * (K_OUT * IN_CH) + ki] = sum;
    }
}

// ---------------------------------------------------------------------------
// Bucket sort by dst-range. meta layout (ints): ghist[0..7], boff[8..16],
// gcursor[17..24].
// ---------------------------------------------------------------------------
__global__ void zero_meta_kernel(int* __restrict__ meta) {
    if (threadIdx.x < 32) meta[threadIdx.x] = 0;
}

__global__ void hist_kernel(const int* __restrict__ dst,
                            int* __restrict__ ghist,
                            int n_edges, int n_nodes) {
    __shared__ int lcnt[NB];
    if (threadIdx.x < NB) lcnt[threadIdx.x] = 0;
    __syncthreads();
    for (int e = blockIdx.x * blockDim.x + threadIdx.x; e < n_edges;
         e += gridDim.x * blockDim.x) {
        int b = (dst[e] * NB) / n_nodes;
        atomicAdd(&lcnt[b], 1);
    }
    __syncthreads();
    if (threadIdx.x < NB) atomicAdd(&ghist[threadIdx.x], lcnt[threadIdx.x]);
}

__global__ void scan_kernel(int* __restrict__ meta) {
    // single thread: NB=8 values
    if (threadIdx.x == 0) {
        int run = 0;
        for (int b = 0; b < NB; ++b) {
            meta[8 + b]  = run;   // boff[b]
            meta[17 + b] = run;   // gcursor[b]
            run += meta[b];       // ghist[b]
        }
        meta[8 + NB] = run;       // boff[NB]
    }
}

// LDS-staged scatter: all global writes coalesced.
__global__ __launch_bounds__(SORT_THREADS)
void scatter_kernel(const int* __restrict__ src,
                    const int* __restrict__ dst,
                    int* __restrict__ meta,
                    int2* __restrict__ rec,
                    int* __restrict__ p,
                    int n_edges, int n_nodes) {
    __shared__ int2 lrec[SORT_TILE];   // 32 KB
    __shared__ int lcnt[NB];
    __shared__ int lofs[NB];
    __shared__ int lbase[NB];

    const int tid = threadIdx.x;
    const int tile0 = blockIdx.x * SORT_TILE;

    if (tid < NB) lcnt[tid] = 0;
    __syncthreads();

    int my_src[EPT], my_dst[EPT], my_rank[EPT], my_b[EPT];
#pragma unroll
    for (int i = 0; i < EPT; ++i) {
        int e = tile0 + i * SORT_THREADS + tid;     // coalesced
        if (e < n_edges) {
            int d = dst[e];
            my_src[i] = src[e];
            my_dst[i] = d;
            int b = (d * NB) / n_nodes;
            my_b[i] = b;
            my_rank[i] = atomicAdd(&lcnt[b], 1);
        } else {
            my_b[i] = -1;
        }
    }
    __syncthreads();
    if (tid == 0) {
        int run = 0;
        for (int b = 0; b < NB; ++b) { lofs[b] = run; run += lcnt[b]; }
    }
    __syncthreads();
    if (tid < NB) lbase[tid] = atomicAdd(&meta[17 + tid], lcnt[tid]);
    __syncthreads();

#pragma unroll
    for (int i = 0; i < EPT; ++i) {
        if (my_b[i] >= 0) {
            int b = my_b[i];
            lrec[lofs[b] + my_rank[i]] = make_int2(my_src[i], my_dst[i]);
            int e = tile0 + i * SORT_THREADS + tid;
            p[e] = lbase[b] + my_rank[i];           // coalesced (indexed by e)
        }
    }
    __syncthreads();

    // contiguous, full-line segment copies
    for (int b = 0; b < NB; ++b) {
        const int cnt = lcnt[b], lo = lofs[b], gb = lbase[b];
        for (int i = tid; i < cnt; i += SORT_THREADS)
            rec[gb + i] = lrec[lo + i];
    }
}

// ---------------------------------------------------------------------------
// Main edge kernel: sorted order, XCD-affine (bucket b processed by blocks
// with blockIdx%8==b so each XCD keeps its 3.2MB z-chunk L2-resident).
// Quad per edge; writes res[pos] coalesced.
// ---------------------------------------------------------------------------
__global__ __launch_bounds__(256)
void edge_kernel_sorted(const float* __restrict__ x,
                        const float* __restrict__ z,
                        const int2* __restrict__ rec,
                        const int* __restrict__ boff,
                        float* __restrict__ res) {
    const int xcd = blockIdx.x & 7;
    const int wid = blockIdx.x >> 3;
    const int nw  = gridDim.x >> 3;
    const int lo = boff[xcd];
    const int hi = boff[xcd + 1];
    const int tq = threadIdx.x >> 2;   // 0..63
    const int l  = threadIdx.x & 3;

    for (int base = lo + wid * 64; base < hi; base += nw * 64) {
        const int pos = base + tq;
        if (pos >= hi) break;

        const int2 r = rec[pos];       // 4 lanes same 8B: L1 broadcast
        const float4* xs = (const float4*)(x + (size_t)r.x * IN_CH) + l * 2;
        const float4* zd = (const float4*)(z + (size_t)r.y * (K_OUT * IN_CH)) + l * 2;

        float4 xa = xs[0];
        float4 xb = xs[1];
        float4 z0a = zd[0],  z0b = zd[1];
        float4 z1a = zd[8],  z1b = zd[9];
        float4 z2a = zd[16], z2b = zd[17];
        float4 z3a = zd[24], z3b = zd[25];

        float p0 = 0.f, p1 = 0.f, p2 = 0.f, p3 = 0.f;
        p0 = fmaf(xa.x, z0a.x, p0); p0 = fmaf(xa.y, z0a.y, p0);
        p0 = fmaf(xa.z, z0a.z, p0); p0 = fmaf(xa.w, z0a.w, p0);
        p0 = fmaf(xb.x, z0b.x, p0); p0 = fmaf(xb.y, z0b.y, p0);
        p0 = fmaf(xb.z, z0b.z, p0); p0 = fmaf(xb.w, z0b.w, p0);

        p1 = fmaf(xa.x, z1a.x, p1); p1 = fmaf(xa.y, z1a.y, p1);
        p1 = fmaf(xa.z, z1a.z, p1); p1 = fmaf(xa.w, z1a.w, p1);
        p1 = fmaf(xb.x, z1b.x, p1); p1 = fmaf(xb.y, z1b.y, p1);
        p1 = fmaf(xb.z, z1b.z, p1); p1 = fmaf(xb.w, z1b.w, p1);

        p2 = fmaf(xa.x, z2a.x, p2); p2 = fmaf(xa.y, z2a.y, p2);
        p2 = fmaf(xa.z, z2a.z, p2); p2 = fmaf(xa.w, z2a.w, p2);
        p2 = fmaf(xb.x, z2b.x, p2); p2 = fmaf(xb.y, z2b.y, p2);
        p2 = fmaf(xb.z, z2b.z, p2); p2 = fmaf(xb.w, z2b.w, p2);

        p3 = fmaf(xa.x, z3a.x, p3); p3 = fmaf(xa.y, z3a.y, p3);
        p3 = fmaf(xa.z, z3a.z, p3); p3 = fmaf(xa.w, z3a.w, p3);
        p3 = fmaf(xb.x, z3b.x, p3); p3 = fmaf(xb.y, z3b.y, p3);
        p3 = fmaf(xb.z, z3b.z, p3); p3 = fmaf(xb.w, z3b.w, p3);

        float send01 = (l & 1) ? p0 : p1;
        float recv01 = __shfl_xor(send01, 1);
        float a01 = ((l & 1) ? p1 : p0) + recv01;
        float send23 = (l & 1) ? p2 : p3;
        float recv23 = __shfl_xor(send23, 1);
        float a23 = ((l & 1) ? p3 : p2) + recv23;
        float send = (l & 2) ? a01 : a23;
        float recv = __shfl_xor(send, 2);
        float v = ((l & 2) ? a23 : a01) + recv;   // lane l = maps[e][l]

        res[(size_t)pos * 4 + l] = tanhf(v);      // coalesced
    }
}

// out[e] = res4[p[e]] : coalesced p-read + out-write; random is a READ.
__global__ void permute_kernel(const float4* __restrict__ res4,
                               const int* __restrict__ p,
                               float4* __restrict__ out4,
                               int n_edges) {
    int e = blockIdx.x * blockDim.x + threadIdx.x;
    if (e >= n_edges) return;
    out4[e] = res4[p[e]];
}

// ---------------------------------------------------------------------------
// Tier-2 (ws fits z only): round-2 unsorted quad kernel.
// ---------------------------------------------------------------------------
__global__ __launch_bounds__(256)
void edge_kernel_quad(const float* __restrict__ x,
                      const float* __restrict__ z,
                      const int* __restrict__ src,
                      const int* __restrict__ dst,
                      float* __restrict__ out,
                      int n_edges) {
    const int t = blockIdx.x * blockDim.x + threadIdx.x;
    const int e = t >> 2;
    const int l = t & 3;
    if (e >= n_edges) return;

    const int s = src[e];
    const int d = dst[e];

    const float4* xs = (const float4*)(x + (size_t)s * IN_CH) + l * 2;
    const float4* zd = (const float4*)(z + (size_t)d * (K_OUT * IN_CH)) + l * 2;

    float4 xa = xs[0];
    float4 xb = xs[1];
    float4 z0a = zd[0],  z0b = zd[1];
    float4 z1a = zd[8],  z1b = zd[9];
    float4 z2a = zd[16], z2b = zd[17];
    float4 z3a = zd[24], z3b = zd[25];

    float p0 = 0.f, p1 = 0.f, p2 = 0.f, p3 = 0.f;
    p0 = fmaf(xa.x, z0a.x, p0); p0 = fmaf(xa.y, z0a.y, p0);
    p0 = fmaf(xa.z, z0a.z, p0); p0 = fmaf(xa.w, z0a.w, p0);
    p0 = fmaf(xb.x, z0b.x, p0); p0 = fmaf(xb.y, z0b.y, p0);
    p0 = fmaf(xb.z, z0b.z, p0); p0 = fmaf(xb.w, z0b.w, p0);

    p1 = fmaf(xa.x, z1a.x, p1); p1 = fmaf(xa.y, z1a.y, p1);
    p1 = fmaf(xa.z, z1a.z, p1); p1 = fmaf(xa.w, z1a.w, p1);
    p1 = fmaf(xb.x, z1b.x, p1); p1 = fmaf(xb.y, z1b.y, p1);
    p1 = fmaf(xb.z, z1b.z, p1); p1 = fmaf(xb.w, z1b.w, p1);

    p2 = fmaf(xa.x, z2a.x, p2); p2 = fmaf(xa.y, z2a.y, p2);
    p2 = fmaf(xa.z, z2a.z, p2); p2 = fmaf(xa.w, z2a.w, p2);
    p2 = fmaf(xb.x, z2b.x, p2); p2 = fmaf(xb.y, z2b.y, p2);
    p2 = fmaf(xb.z, z2b.z, p2); p2 = fmaf(xb.w, z2b.w, p2);

    p3 = fmaf(xa.x, z3a.x, p3); p3 = fmaf(xa.y, z3a.y, p3);
    p3 = fmaf(xa.z, z3a.z, p3); p3 = fmaf(xa.w, z3a.w, p3);
    p3 = fmaf(xb.x, z3b.x, p3); p3 = fmaf(xb.y, z3b.y, p3);
    p3 = fmaf(xb.z, z3b.z, p3); p3 = fmaf(xb.w, z3b.w, p3);

    float send01 = (l & 1) ? p0 : p1;
    float recv01 = __shfl_xor(send01, 1);
    float a01 = ((l & 1) ? p1 : p0) + recv01;
    float send23 = (l & 1) ? p2 : p3;
    float recv23 = __shfl_xor(send23, 1);
    float a23 = ((l & 1) ? p3 : p2) + recv23;
    float send = (l & 2) ? a01 : a23;
    float recv = __shfl_xor(send, 2);
    float r = ((l & 2) ? a23 : a01) + recv;

    out[t] = tanhf(r);
}

// ---------------------------------------------------------------------------
// Tier-3 fallback: direct quadratic form per edge (no workspace).
// ---------------------------------------------------------------------------
__global__ void edge_direct_kernel(const float* __restrict__ x,
                                   const float* __restrict__ T,
                                   const int* __restrict__ src,
                                   const int* __restrict__ dst,
                                   float* __restrict__ out,
                                   int n_edges) {
    int e = blockIdx.x * blockDim.x + threadIdx.x;
    if (e >= n_edges) return;

    const int s = src[e];
    const int d = dst[e];

    float xs[IN_CH], xd[IN_CH];
#pragma unroll
    for (int j = 0; j < IN_CH; ++j) {
        xs[j] = x[(size_t)s * IN_CH + j];
        xd[j] = x[(size_t)d * IN_CH + j];
    }

    float resv[K_OUT];
#pragma unroll
    for (int k = 0; k < K_OUT; ++k) {
        float acc = 0.f;
        for (int i = 0; i < IN_CH; ++i) {
            const float* Trow = T + ((size_t)k * IN_CH + i) * IN_CH;
            float yi = 0.f;
#pragma unroll
            for (int j = 0; j < IN_CH; ++j)
                yi = fmaf(Trow[j], xd[j], yi);
            acc = fmaf(xs[i], yi, acc);
        }
        resv[k] = tanhf(acc);
    }
    ((float4*)out)[e] = make_float4(resv[0], resv[1], resv[2], resv[3]);
}

extern "C" void kernel_launch(void* const* d_in, const int* in_sizes, int n_in,
                              void* d_out, int out_size, void* d_ws, size_t ws_size,
                              hipStream_t stream) {
    const float* x  = (const float*)d_in[0];
    const int*   ei = (const int*)d_in[1];
    const float* T  = (const float*)d_in[2];
    float* out      = (float*)d_out;

    const int n_nodes = in_sizes[0] / IN_CH;
    const int n_edges = in_sizes[1] / 2;
    const int* src = ei;
    const int* dst = ei + n_edges;

    // Workspace layout (all 256B-aligned)
    const size_t z_bytes  = (size_t)n_nodes * K_OUT * IN_CH * sizeof(float);
    const size_t meta_off = (z_bytes + 255) & ~(size_t)255;
    const size_t rec_off  = meta_off + 256;
    const size_t p_off    = rec_off + (((size_t)n_edges * sizeof(int2) + 255) & ~(size_t)255);
    const size_t res_off  = p_off + (((size_t)n_edges * sizeof(int) + 255) & ~(size_t)255);
    const size_t need_full = res_off + (size_t)n_edges * K_OUT * sizeof(float);

    const int threads = 256;
    const int eblocks = (n_edges + threads - 1) / threads;

    if (ws_size >= need_full) {
        float* z    = (float*)d_ws;
        int*   meta = (int*)((char*)d_ws + meta_off);    // ghist[0..7] boff[8..16] gcur[17..24]
        int2*  rec  = (int2*)((char*)d_ws + rec_off);
        int*   p    = (int*)((char*)d_ws + p_off);
        float* res  = (float*)((char*)d_ws + res_off);

        precompute_z_kernel<<<1024, 128, 0, stream>>>(x, T, z, n_nodes);
        zero_meta_kernel<<<1, 64, 0, stream>>>(meta);
        hist_kernel<<<1024, 256, 0, stream>>>(dst, meta, n_edges, n_nodes);
        scan_kernel<<<1, 64, 0, stream>>>(meta);
        scatter_kernel<<<(n_edges + SORT_TILE - 1) / SORT_TILE, SORT_THREADS, 0, stream>>>(
            src, dst, meta, rec, p, n_edges, n_nodes);
        edge_kernel_sorted<<<2048, 256, 0, stream>>>(x, z, rec, meta + 8, res);
        permute_kernel<<<eblocks, threads, 0, stream>>>(
            (const float4*)res, p, (float4*)out, n_edges);
    } else if (ws_size >= z_bytes) {
        float* z = (float*)d_ws;
        precompute_z_kernel<<<1024, 128, 0, stream>>>(x, T, z, n_nodes);
        const long long total = (long long)n_edges * 4;
        const int blocks = (int)((total + threads - 1) / threads);
        edge_kernel_quad<<<blocks, threads, 0, stream>>>(x, z, src, dst, out, n_edges);
    } else {
        edge_direct_kernel<<<eblocks, threads, 0, stream>>>(x, T, src, dst, out, n_edges);
    }
}